// Round 2
// baseline (833.480 us; speedup 1.0000x reference)
//
#include <hip/hip_runtime.h>

// Problem constants (fixed by the reference)
#define B_  4
#define SQ_ 4096
#define SK_ 462
#define H_  10
#define DH_ 64
#define D_  (H_ * DH_)   // 640
#define SKP_ 480         // keys padded to 15*32
#define KT_  15          // key chunks of 32

typedef _Float16 half8 __attribute__((ext_vector_type(8)));
typedef float floatx4 __attribute__((ext_vector_type(4)));

// workspace layout: f16 K at +0; f16 V^T after (flag lives in a device global)
#define K16_ELEMS ((size_t)B_ * H_ * SKP_ * DH_)            // 1,228,800 halves
#define WS_NEEDED (2 * K16_ELEMS * sizeof(_Float16))

// mask_bool storage format: 0 = int32 per element, 1 = byte per element,
// 2 = float32 per element. (0 and 2 both decode as "dword != 0".)
__device__ int g_mask_fmt;

__global__ void detect_mask_fmt(const unsigned int* __restrict__ mb_dw) {
  __shared__ int s_float, s_byte;
  if (threadIdx.x == 0) { s_float = 0; s_byte = 0; }
  __syncthreads();
  int fl = 0, by = 0;
  for (int i = threadIdx.x; i < 1024; i += 256) {
    unsigned int x = mb_dw[i];
    if (x > 1u) {
      if (x == 0x3F800000u) fl = 1; else by = 1;
    }
  }
  if (fl) atomicOr(&s_float, 1);
  if (by) atomicOr(&s_byte, 1);
  __syncthreads();
  if (threadIdx.x == 0) g_mask_fmt = s_float ? 2 : (s_byte ? 1 : 0);
}

__device__ __forceinline__ half8 cvt8(float4 a, float4 b) {
  half8 o;
  o[0] = (_Float16)a.x; o[1] = (_Float16)a.y;
  o[2] = (_Float16)a.z; o[3] = (_Float16)a.w;
  o[4] = (_Float16)b.x; o[5] = (_Float16)b.y;
  o[6] = (_Float16)b.z; o[7] = (_Float16)b.w;
  return o;
}

// ---------------------------------------------------------------------------
// One-time K/V conversion:
//   k16 [b][h][key(480)][d(64)]  f16, 128B rows  -> QK^T B-fragments = dwordx4
//   vt16[b][h][d(64)][key(480)]  f16, 960B rows  -> PV   B-fragments = dwordx4
// Padding keys 462..479 are zero (V MUST be zero so P=0 rows stay finite).
// ---------------------------------------------------------------------------
__global__ void convert_kv(const float* __restrict__ k, const float* __restrict__ v,
                           _Float16* __restrict__ k16, _Float16* __restrict__ vt16) {
  int t = blockIdx.x * 256 + threadIdx.x;
  const int NK = B_ * H_ * SKP_ * (DH_ / 8);   // 153600 half8-groups for K
  const int NV = B_ * H_ * DH_ * (SKP_ / 8);   // 153600 half8-groups for V^T
  if (t < NK) {
    int d8  = t & 7;                // 8 groups of 8 halves per 64-dim row
    int key = (t >> 3) % SKP_;
    int bh  = t / (8 * SKP_);
    int b = bh / H_, h = bh % H_;
    half8 o;
    if (key < SK_) {
      const float* src = k + ((size_t)(b * SK_ + key)) * D_ + h * DH_ + d8 * 8;
      float4 f0 = *reinterpret_cast<const float4*>(src);
      float4 f1 = *reinterpret_cast<const float4*>(src + 4);
      o = cvt8(f0, f1);
    } else {
      #pragma unroll
      for (int j = 0; j < 8; ++j) o[j] = (_Float16)0.0f;
    }
    *reinterpret_cast<half8*>(k16 + ((size_t)bh * SKP_ + key) * DH_ + d8 * 8) = o;
  } else if (t < NK + NV) {
    int u  = t - NK;
    int k8 = u % (SKP_ / 8);        // 60 groups of 8 keys
    int d  = (u / (SKP_ / 8)) % DH_;
    int bh = u / ((SKP_ / 8) * DH_);
    int b = bh / H_, h = bh % H_;
    half8 o;
    #pragma unroll
    for (int j = 0; j < 8; ++j) {
      int key = k8 * 8 + j;
      o[j] = (key < SK_)
               ? (_Float16)v[((size_t)(b * SK_ + key)) * D_ + h * DH_ + d]
               : (_Float16)0.0f;
    }
    *reinterpret_cast<half8*>(vt16 + ((size_t)bh * DH_ + d) * SKP_ + k8 * 8) = o;
  }
}

// ---------------------------------------------------------------------------
// Barrier-free flash attention.
// grid = (SQ/64, H, B), block = 256 (4 independent waves; wave owns 16 rows).
// mfma_f32_16x16x32_f16: A[m=lane&15][k=(lane>>4)*8+j],
//   B[k=(lane>>4)*8+j][n=lane&15], C/D: col=lane&15, row=(lane>>4)*4+reg.
// Masks for iteration kt+1 are issued AFTER this iteration's K/V fragment
// loads so the compiler's counted s_waitcnt vmcnt(N) keeps them in flight
// across the whole iteration (vmcnt retires in order).
// ---------------------------------------------------------------------------
template<bool WS, bool MBYTE>
__device__ __forceinline__ void attn_body(
    const float* __restrict__ q, const float* __restrict__ k,
    const float* __restrict__ v, const void* __restrict__ mb,
    const float* __restrict__ msc, float* __restrict__ out,
    const _Float16* __restrict__ k16, const _Float16* __restrict__ vt16,
    _Float16 (&ps)[4][16][34]) {
  const int tid  = threadIdx.x;
  const int wave = tid >> 6;
  const int lane = tid & 63;
  const int l16  = lane & 15;
  const int g4   = lane >> 4;

  const int b  = blockIdx.z;
  const int h  = blockIdx.y;
  const int q0 = blockIdx.x * 64;
  const int bh = b * H_ + h;

  // ---- Q A-fragments straight from global (one-time, 16B-aligned) ----
  half8 aq[2];
  {
    const float* qp = q + ((size_t)(b * SQ_ + q0 + wave * 16 + l16)) * D_ + h * DH_;
    #pragma unroll
    for (int kk = 0; kk < 2; ++kk) {
      float4 f0 = *reinterpret_cast<const float4*>(qp + kk * 32 + g4 * 8);
      float4 f1 = *reinterpret_cast<const float4*>(qp + kk * 32 + g4 * 8 + 4);
      aq[kk] = cvt8(f0, f1);
    }
  }

  floatx4 o_acc[4];
  floatx4 l_acc;
  #pragma unroll
  for (int nt = 0; nt < 4; ++nt)
    #pragma unroll
    for (int r = 0; r < 4; ++r) o_acc[nt][r] = 0.0f;
  #pragma unroll
  for (int r = 0; r < 4; ++r) l_acc[r] = 0.0f;
  float m2[4] = {-1e30f, -1e30f, -1e30f, -1e30f};   // running max, base-2 domain

  unsigned int rowoff[4];
  #pragma unroll
  for (int r = 0; r < 4; ++r) {
    int qrow = q0 + wave * 16 + g4 * 4 + r;
    rowoff[r] = (unsigned int)((b * H_ + h) * SQ_ + qrow) * SK_;
  }

  half8 ones_f;
  #pragma unroll
  for (int j = 0; j < 8; ++j) ones_f[j] = (_Float16)1.0f;

  const float c2 = 0.18033688011112042f;  // (1/sqrt(64)) * log2(e)

  const unsigned char* mbb = (const unsigned char*)mb;
  const unsigned int*  mbd = (const unsigned int*)mb;

  // mask folded into scale: m_ == 0.0f  <=>  masked out (mask_scale >= 1.0)
  auto load_masks = [&](int kt_, float (&m_)[2][4]) {
    #pragma unroll
    for (int ct = 0; ct < 2; ++ct)
      #pragma unroll
      for (int r = 0; r < 4; ++r) {
        int col = kt_ * 32 + ct * 16 + l16;
        int cc  = col < SK_ ? col : SK_ - 1;
        unsigned int idx = rowoff[r] + (unsigned int)cc;
        float sc = msc[idx];
        unsigned int mvv = MBYTE ? (unsigned int)mbb[idx] : mbd[idx];
        m_[ct][r] = (mvv != 0u && col < SK_) ? sc : 0.0f;
      }
  };

  float mC[2][4];
  load_masks(0, mC);

  const _Float16* kbase16 = k16 + (size_t)bh * SKP_ * DH_;
  const _Float16* vbase16 = vt16 + (size_t)bh * DH_ * SKP_;
  const float* kbase = k + (size_t)(b * SK_) * D_ + h * DH_;
  const float* vbase = v + (size_t)(b * SK_) * D_ + h * DH_;

  for (int kt = 0; kt < KT_; ++kt) {
    // ---- 1) K fragments (issued first: retire first in vmcnt order) ----
    half8 kbf[2][2];
    if constexpr (WS) {
      const _Float16* kp = kbase16 + (size_t)(kt * 32) * DH_;
      #pragma unroll
      for (int ct = 0; ct < 2; ++ct)
        #pragma unroll
        for (int kk = 0; kk < 2; ++kk)
          kbf[ct][kk] = *reinterpret_cast<const half8*>(
              kp + (ct * 16 + l16) * DH_ + kk * 32 + g4 * 8);
    } else {
      #pragma unroll
      for (int ct = 0; ct < 2; ++ct) {
        int key = kt * 32 + ct * 16 + l16;
        int kc  = key < SK_ ? key : SK_ - 1;
        #pragma unroll
        for (int kk = 0; kk < 2; ++kk) {
          const float* kp = kbase + (size_t)kc * D_ + kk * 32 + g4 * 8;
          float4 f0 = *reinterpret_cast<const float4*>(kp);
          float4 f1 = *reinterpret_cast<const float4*>(kp + 4);
          kbf[ct][kk] = cvt8(f0, f1);
        }
      }
    }

    // ---- 2) V fragments ----
    half8 vbf[4];
    if constexpr (WS) {
      const _Float16* vp = vbase16 + kt * 32 + g4 * 8;
      #pragma unroll
      for (int nt = 0; nt < 4; ++nt)
        vbf[nt] = *reinterpret_cast<const half8*>(vp + (size_t)(nt * 16 + l16) * SKP_);
    } else {
      #pragma unroll
      for (int nt = 0; nt < 4; ++nt) {
        int dim = nt * 16 + l16;
        #pragma unroll
        for (int j = 0; j < 8; ++j) {
          int key = kt * 32 + g4 * 8 + j;
          vbf[nt][j] = (key < SK_)
                         ? (_Float16)vbase[(size_t)key * D_ + dim]
                         : (_Float16)0.0f;
        }
      }
    }

    // ---- 3) prefetch NEXT iteration's masks (stay in flight all iter) ----
    float mN[2][4];
    if (kt + 1 < KT_) load_masks(kt + 1, mN);

    // ---- 4) S = Q K^T ----
    floatx4 s[2];
    #pragma unroll
    for (int ct = 0; ct < 2; ++ct)
      #pragma unroll
      for (int r = 0; r < 4; ++r) s[ct][r] = 0.0f;
    #pragma unroll
    for (int ct = 0; ct < 2; ++ct)
      #pragma unroll
      for (int kk = 0; kk < 2; ++kk)
        s[ct] = __builtin_amdgcn_mfma_f32_16x16x32_f16(aq[kk], kbf[ct][kk], s[ct], 0, 0, 0);

    // ---- 5) online softmax (base-2), masks from previous-iter prefetch ----
    float pw[2][4];
    #pragma unroll
    for (int r = 0; r < 4; ++r) {
      float sc0 = mC[0][r], sc1 = mC[1][r];
      float s0 = (sc0 != 0.0f) ? s[0][r] * (c2 * sc0) : -1e30f;
      float s1 = (sc1 != 0.0f) ? s[1][r] * (c2 * sc1) : -1e30f;
      float mx = fmaxf(s0, s1);
      mx = fmaxf(mx, __shfl_xor(mx, 1));
      mx = fmaxf(mx, __shfl_xor(mx, 2));
      mx = fmaxf(mx, __shfl_xor(mx, 4));
      mx = fmaxf(mx, __shfl_xor(mx, 8));
      float mnew  = fmaxf(m2[r], mx);
      float alpha = exp2f(m2[r] - mnew);
      m2[r] = mnew;
      pw[0][r] = exp2f(s0 - mnew);   // masked: exp2(-1e30 - finite) == +0
      pw[1][r] = exp2f(s1 - mnew);
      l_acc[r] *= alpha;
      #pragma unroll
      for (int nt = 0; nt < 4; ++nt) o_acc[nt][r] *= alpha;
    }

    // ---- 6) P: C-layout -> A-layout via per-wave LDS (no barrier) ----
    #pragma unroll
    for (int ct = 0; ct < 2; ++ct)
      #pragma unroll
      for (int r = 0; r < 4; ++r)
        ps[wave][g4 * 4 + r][ct * 16 + l16] = (_Float16)pw[ct][r];
    asm volatile("s_waitcnt lgkmcnt(0)" ::: "memory");  // wave-local write->read
    half8 pa;
    #pragma unroll
    for (int j = 0; j < 8; ++j) pa[j] = ps[wave][l16][g4 * 8 + j];

    // ---- 7) O += P V ; l += rowsum(P) via ones-column MFMA ----
    #pragma unroll
    for (int nt = 0; nt < 4; ++nt)
      o_acc[nt] = __builtin_amdgcn_mfma_f32_16x16x32_f16(pa, vbf[nt], o_acc[nt], 0, 0, 0);
    l_acc = __builtin_amdgcn_mfma_f32_16x16x32_f16(pa, ones_f, l_acc, 0, 0, 0);

    // ---- 8) rotate prefetched masks ----
    if (kt + 1 < KT_) {
      #pragma unroll
      for (int ct = 0; ct < 2; ++ct)
        #pragma unroll
        for (int r = 0; r < 4; ++r) mC[ct][r] = mN[ct][r];
    }
  }

  // ---- epilogue: normalize and store (16-lane, 64B coalesced segments) ----
  #pragma unroll
  for (int r = 0; r < 4; ++r) {
    float inv = 1.0f / l_acc[r];
    int qrow = q0 + wave * 16 + g4 * 4 + r;
    float* ob = out + (size_t)(b * SQ_ + qrow) * D_ + h * DH_;
    #pragma unroll
    for (int nt = 0; nt < 4; ++nt)
      ob[nt * 16 + l16] = o_acc[nt][r] * inv;
  }
}

template<bool WS>
__global__ __launch_bounds__(256, 3)
void attn_fwd(const float* __restrict__ q, const float* __restrict__ k,
              const float* __restrict__ v, const void* __restrict__ mb,
              const float* __restrict__ msc, float* __restrict__ out,
              const _Float16* __restrict__ k16, const _Float16* __restrict__ vt16) {
  __shared__ __align__(16) _Float16 ps[4][16][34];   // only LDS: 4.25 KB
  if (g_mask_fmt == 1) attn_body<WS, true >(q, k, v, mb, msc, out, k16, vt16, ps);
  else                 attn_body<WS, false>(q, k, v, mb, msc, out, k16, vt16, ps);
}

extern "C" void kernel_launch(void* const* d_in, const int* in_sizes, int n_in,
                              void* d_out, int out_size, void* d_ws, size_t ws_size,
                              hipStream_t stream) {
  const float* q   = (const float*)d_in[0];
  const float* k   = (const float*)d_in[1];
  const float* v   = (const float*)d_in[2];
  const void*  mb  = d_in[3];          // mask_bool: storage format auto-detected
  const float* msc = (const float*)d_in[4];
  // d_in[5] = heads (==10), constant for this problem
  float* out = (float*)d_out;

  detect_mask_fmt<<<1, 256, 0, stream>>>((const unsigned int*)mb);

  _Float16* k16  = (_Float16*)d_ws;
  _Float16* vt16 = k16 + K16_ELEMS;

  dim3 grid(SQ_ / 64, H_, B_);
  if (d_ws != nullptr && ws_size >= WS_NEEDED) {
    // 2 * 153600 half8-groups / 256 threads = 1200 blocks
    convert_kv<<<1200, 256, 0, stream>>>(k, v, k16, vt16);
    attn_fwd<true><<<grid, 256, 0, stream>>>(q, k, v, mb, msc, out, k16, vt16);
  } else {
    attn_fwd<false><<<grid, 256, 0, stream>>>(q, k, v, mb, msc, out, k16, vt16);
  }
}

// Round 3
// 822.215 us; speedup vs baseline: 1.0137x; 1.0137x over previous
//
#include <hip/hip_runtime.h>

// Problem constants (fixed by the reference)
#define B_  4
#define SQ_ 4096
#define SK_ 462
#define H_  10
#define DH_ 64
#define D_  (H_ * DH_)   // 640
#define SKP_ 480         // keys padded to 15*32
#define KT_  15          // key chunks of 32
#define MBDW_ 16         // bitmask dwords per row (15 used, padded to 16 = 64B)

typedef _Float16 half8 __attribute__((ext_vector_type(8)));
typedef float floatx4 __attribute__((ext_vector_type(4)));
typedef float float2v __attribute__((ext_vector_type(2)));

// workspace layout: f16 K | f16 V^T | bitmask
#define K16_ELEMS ((size_t)B_ * H_ * SKP_ * DH_)            // 1,228,800 halves
#define MBITS_DW  ((size_t)B_ * H_ * SQ_ * MBDW_)           // 2,621,440 dwords
#define WS_KV     (2 * K16_ELEMS * sizeof(_Float16))        // 4.9 MB
#define WS_FULL   (WS_KV + MBITS_DW * 4)                    // 15.4 MB

// mask_bool storage format: 0 = int32, 1 = byte, 2 = float32 per element.
__device__ int g_mask_fmt;

__global__ void detect_mask_fmt(const unsigned int* __restrict__ mb_dw) {
  __shared__ int s_float, s_byte;
  if (threadIdx.x == 0) { s_float = 0; s_byte = 0; }
  __syncthreads();
  int fl = 0, by = 0;
  for (int i = threadIdx.x; i < 1024; i += 256) {
    unsigned int x = mb_dw[i];
    if (x > 1u) {
      if (x == 0x3F800000u) fl = 1; else by = 1;
    }
  }
  if (fl) atomicOr(&s_float, 1);
  if (by) atomicOr(&s_byte, 1);
  __syncthreads();
  if (threadIdx.x == 0) g_mask_fmt = s_float ? 2 : (s_byte ? 1 : 0);
}

__device__ __forceinline__ half8 cvt8(float4 a, float4 b) {
  half8 o;
  o[0] = (_Float16)a.x; o[1] = (_Float16)a.y;
  o[2] = (_Float16)a.z; o[3] = (_Float16)a.w;
  o[4] = (_Float16)b.x; o[5] = (_Float16)b.y;
  o[6] = (_Float16)b.z; o[7] = (_Float16)b.w;
  return o;
}

// ---------------------------------------------------------------------------
// One-time K/V conversion (unchanged from prior round):
//   k16 [b][h][key(480)][d(64)]  f16 -> QK^T B-fragments = dwordx4
//   vt16[b][h][d(64)][key(480)]  f16 -> PV   B-fragments = dwordx4
// ---------------------------------------------------------------------------
__global__ void convert_kv(const float* __restrict__ k, const float* __restrict__ v,
                           _Float16* __restrict__ k16, _Float16* __restrict__ vt16) {
  int t = blockIdx.x * 256 + threadIdx.x;
  const int NK = B_ * H_ * SKP_ * (DH_ / 8);
  const int NV = B_ * H_ * DH_ * (SKP_ / 8);
  if (t < NK) {
    int d8  = t & 7;
    int key = (t >> 3) % SKP_;
    int bh  = t / (8 * SKP_);
    int b = bh / H_, h = bh % H_;
    half8 o;
    if (key < SK_) {
      const float* src = k + ((size_t)(b * SK_ + key)) * D_ + h * DH_ + d8 * 8;
      float4 f0 = *reinterpret_cast<const float4*>(src);
      float4 f1 = *reinterpret_cast<const float4*>(src + 4);
      o = cvt8(f0, f1);
    } else {
      #pragma unroll
      for (int j = 0; j < 8; ++j) o[j] = (_Float16)0.0f;
    }
    *reinterpret_cast<half8*>(k16 + ((size_t)bh * SKP_ + key) * DH_ + d8 * 8) = o;
  } else if (t < NK + NV) {
    int u  = t - NK;
    int k8 = u % (SKP_ / 8);
    int d  = (u / (SKP_ / 8)) % DH_;
    int bh = u / ((SKP_ / 8) * DH_);
    int b = bh / H_, h = bh % H_;
    half8 o;
    #pragma unroll
    for (int j = 0; j < 8; ++j) {
      int key = k8 * 8 + j;
      o[j] = (key < SK_)
               ? (_Float16)v[((size_t)(b * SK_ + key)) * D_ + h * DH_ + d]
               : (_Float16)0.0f;
    }
    *reinterpret_cast<half8*>(vt16 + ((size_t)bh * DH_ + d) * SKP_ + k8 * 8) = o;
  }
}

// ---------------------------------------------------------------------------
// mask_bool -> bitmask: mbits[row][dw] bit j = mask[row][dw*32+j]; cols >= 462
// are 0. One wave packs one row-group of 16 rows via __ballot (coalesced).
// Rows enumerate (b,h,q) flat: row = (b*H + h)*SQ + q.  163840 rows total.
// ---------------------------------------------------------------------------
__global__ __launch_bounds__(256)
void build_mbits(const void* __restrict__ mb, unsigned int* __restrict__ mbits) {
  const int fmt  = g_mask_fmt;
  const int lane = threadIdx.x & 63;
  const int wgid = (blockIdx.x * 256 + threadIdx.x) >> 6;   // 0..10239
  const unsigned char* mbb = (const unsigned char*)mb;
  const unsigned int*  mbd = (const unsigned int*)mb;
  for (int rr = 0; rr < 16; ++rr) {
    int row = wgid * 16 + rr;                               // 0..163839
    size_t rb = (size_t)row * SK_;
    #pragma unroll
    for (int i = 0; i < 8; ++i) {                           // 8*64 = 512 cols
      int col = i * 64 + lane;
      int mv = 0;
      if (col < SK_) mv = (fmt == 1) ? (mbb[rb + col] != 0) : (mbd[rb + col] != 0u);
      unsigned long long bal = __ballot(mv);
      if (lane == 0)  mbits[(size_t)row * MBDW_ + i * 2]     = (unsigned int)bal;
      if (lane == 32) mbits[(size_t)row * MBDW_ + i * 2 + 1] = (unsigned int)(bal >> 32);
    }
  }
}

// ---------------------------------------------------------------------------
// FULL-path flash attention. Barrier-free; 4 independent waves per block.
// HBM stream in the loop is ONLY mask_scale, loaded wide (dwordx2 per lane,
// 16 rows x 2ish lines per instruction) 2 iterations deep into registers,
// then transposed through a per-wave LDS tile to the C-layout consumers.
// Mask bits come from the preprocessed bitmask, staged once in LDS.
// mfma_f32_16x16x32_f16: A[m=lane&15][k=(lane>>4)*8+j],
//   B[k=(lane>>4)*8+j][n=lane&15], C/D: col=lane&15, row=(lane>>4)*4+reg.
// ---------------------------------------------------------------------------
__global__ __launch_bounds__(256, 4)
void attn_fwd_full(const float* __restrict__ q, const float* __restrict__ msc,
                   float* __restrict__ out,
                   const _Float16* __restrict__ k16, const _Float16* __restrict__ vt16,
                   const unsigned int* __restrict__ mbits) {
  __shared__ __align__(16) _Float16     ps[4][16][34];   // P relayout (4.25 KB)
  __shared__ __align__(16) float        ms[4][16][34];   // msc tile    (8.7 KB)
  __shared__ __align__(16) unsigned int mbl[4][16][16];  // bitmask     (4 KB)

  const int tid  = threadIdx.x;
  const int wave = tid >> 6;
  const int lane = tid & 63;
  const int l16  = lane & 15;
  const int g4   = lane >> 4;

  const int b  = blockIdx.z;
  const int h  = blockIdx.y;
  const int q0 = blockIdx.x * 64;
  const int bh = b * H_ + h;

  // ---- Q A-fragments straight from global (one-time, 16B-aligned) ----
  half8 aq[2];
  {
    const float* qp = q + ((size_t)(b * SQ_ + q0 + wave * 16 + l16)) * D_ + h * DH_;
    #pragma unroll
    for (int kk = 0; kk < 2; ++kk) {
      float4 f0 = *reinterpret_cast<const float4*>(qp + kk * 32 + g4 * 8);
      float4 f1 = *reinterpret_cast<const float4*>(qp + kk * 32 + g4 * 8 + 4);
      aq[kk] = cvt8(f0, f1);
    }
  }

  // ---- bitmask prologue: wave's 16 rows x 16 dwords -> LDS (wave-local) ----
  {
    int i = lane >> 2, c4 = (lane & 3) * 4;
    size_t row = (size_t)bh * SQ_ + (q0 + wave * 16 + i);
    uint4 w = *reinterpret_cast<const uint4*>(mbits + row * MBDW_ + c4);
    *reinterpret_cast<uint4*>(&mbl[wave][i][c4]) = w;
  }

  floatx4 o_acc[4];
  floatx4 l_acc;
  #pragma unroll
  for (int nt = 0; nt < 4; ++nt)
    #pragma unroll
    for (int r = 0; r < 4; ++r) o_acc[nt][r] = 0.0f;
  #pragma unroll
  for (int r = 0; r < 4; ++r) l_acc[r] = 0.0f;
  float m2[4] = {-1e30f, -1e30f, -1e30f, -1e30f};

  half8 ones_f;
  #pragma unroll
  for (int j = 0; j < 8; ++j) ones_f[j] = (_Float16)1.0f;

  const float c2 = 0.18033688011112042f;  // (1/sqrt(64)) * log2(e)

  // ---- msc wide loader: lane -> (row = lane>>2, 4 x float2 chunks) ----
  // byte addr = 4*(row*462 + c), row*462 even, c even -> 8B aligned always.
  const size_t mrow = ((size_t)bh * SQ_ + (q0 + wave * 16 + (lane >> 2))) * SK_;
  float2v rA[4], rB[4];
  auto issue_msc = [&](int kt_, float2v (&rg)[4]) {
    #pragma unroll
    for (int p = 0; p < 4; ++p) {
      int c = kt_ * 32 + ((lane & 3) + p * 4) * 2;
      c = (c <= SK_ - 2) ? c : (SK_ - 2);   // clamp (even -> stays 8B aligned);
      rg[p] = *reinterpret_cast<const float2v*>(msc + mrow + c);  // garbage masked by bits
    }
  };
  auto write_tile = [&](float2v (&rg)[4]) {
    int i = lane >> 2;
    #pragma unroll
    for (int p = 0; p < 4; ++p) {
      int c = ((lane & 3) + p * 4) * 2;     // even; ms row stride 34 -> 8B aligned
      *reinterpret_cast<float2v*>(&ms[wave][i][c]) = rg[p];
    }
  };

  issue_msc(0, rA);                 // in flight
  issue_msc(1, rB);                 // in flight
  write_tile(rA);                   // tile <- msc(0)  (compiler inserts vm wait)
  #pragma unroll
  for (int p = 0; p < 4; ++p) rA[p] = rB[p];   // rA := msc(1)

  const _Float16* kbase16 = k16 + (size_t)bh * SKP_ * DH_;
  const _Float16* vbase16 = vt16 + (size_t)bh * DH_ * SKP_;

  for (int kt = 0; kt < KT_; ++kt) {
    // ---- 1) issue msc loads for kt+2; pin them at loop top ----
    if (kt + 2 < KT_) issue_msc(kt + 2, rB);
    __builtin_amdgcn_sched_barrier(0);

    // ---- 2) K fragments from workspace f16 (L2-resident) ----
    half8 kbf[2][2];
    {
      const _Float16* kp = kbase16 + (size_t)(kt * 32) * DH_;
      #pragma unroll
      for (int ct = 0; ct < 2; ++ct)
        #pragma unroll
        for (int kk = 0; kk < 2; ++kk)
          kbf[ct][kk] = *reinterpret_cast<const half8*>(
              kp + (ct * 16 + l16) * DH_ + kk * 32 + g4 * 8);
    }
    // ---- 3) V fragments ----
    half8 vbf[4];
    {
      const _Float16* vp = vbase16 + kt * 32 + g4 * 8;
      #pragma unroll
      for (int nt = 0; nt < 4; ++nt)
        vbf[nt] = *reinterpret_cast<const half8*>(vp + (size_t)(nt * 16 + l16) * SKP_);
    }

    // ---- 4) S = Q K^T ----
    floatx4 s[2];
    #pragma unroll
    for (int ct = 0; ct < 2; ++ct)
      #pragma unroll
      for (int r = 0; r < 4; ++r) s[ct][r] = 0.0f;
    #pragma unroll
    for (int ct = 0; ct < 2; ++ct)
      #pragma unroll
      for (int kk = 0; kk < 2; ++kk)
        s[ct] = __builtin_amdgcn_mfma_f32_16x16x32_f16(aq[kk], kbf[ct][kk], s[ct], 0, 0, 0);

    // ---- 5) fold mask+scale from LDS (mC==0 <=> masked; msc >= 1) ----
    float mC[2][4];
    #pragma unroll
    for (int r = 0; r < 4; ++r) {
      unsigned int mw = mbl[wave][g4 * 4 + r][kt];
      float v0 = ms[wave][g4 * 4 + r][l16];
      float v1 = ms[wave][g4 * 4 + r][16 + l16];
      mC[0][r] = ((mw >> l16) & 1u)        ? v0 : 0.0f;
      mC[1][r] = ((mw >> (16 + l16)) & 1u) ? v1 : 0.0f;
    }

    // ---- 6) online softmax (base-2) ----
    float pw[2][4];
    #pragma unroll
    for (int r = 0; r < 4; ++r) {
      float sc0 = mC[0][r], sc1 = mC[1][r];
      float s0 = (sc0 != 0.0f) ? s[0][r] * (c2 * sc0) : -1e30f;
      float s1 = (sc1 != 0.0f) ? s[1][r] * (c2 * sc1) : -1e30f;
      float mx = fmaxf(s0, s1);
      mx = fmaxf(mx, __shfl_xor(mx, 1));
      mx = fmaxf(mx, __shfl_xor(mx, 2));
      mx = fmaxf(mx, __shfl_xor(mx, 4));
      mx = fmaxf(mx, __shfl_xor(mx, 8));
      float mnew  = fmaxf(m2[r], mx);
      float alpha = exp2f(m2[r] - mnew);
      m2[r] = mnew;
      pw[0][r] = exp2f(s0 - mnew);
      pw[1][r] = exp2f(s1 - mnew);
      l_acc[r] *= alpha;
      #pragma unroll
      for (int nt = 0; nt < 4; ++nt) o_acc[nt][r] *= alpha;
    }

    // ---- 7) P: C-layout -> A-layout via per-wave LDS (no barrier) ----
    #pragma unroll
    for (int ct = 0; ct < 2; ++ct)
      #pragma unroll
      for (int r = 0; r < 4; ++r)
        ps[wave][g4 * 4 + r][ct * 16 + l16] = (_Float16)pw[ct][r];
    asm volatile("s_waitcnt lgkmcnt(0)" ::: "memory");
    half8 pa;
    #pragma unroll
    for (int j = 0; j < 8; ++j) pa[j] = ps[wave][l16][g4 * 8 + j];

    // ---- 8) O += P V ; l += rowsum(P) ----
    #pragma unroll
    for (int nt = 0; nt < 4; ++nt)
      o_acc[nt] = __builtin_amdgcn_mfma_f32_16x16x32_f16(pa, vbf[nt], o_acc[nt], 0, 0, 0);
    l_acc = __builtin_amdgcn_mfma_f32_16x16x32_f16(pa, ones_f, l_acc, 0, 0, 0);

    // ---- 9) stage msc(kt+1) into tile (after this iter's tile reads) ----
    if (kt + 1 < KT_) {
      write_tile(rA);
      #pragma unroll
      for (int p = 0; p < 4; ++p) rA[p] = rB[p];
    }
  }

  // ---- epilogue: normalize and store ----
  #pragma unroll
  for (int r = 0; r < 4; ++r) {
    float inv = 1.0f / l_acc[r];
    int qrow = q0 + wave * 16 + g4 * 4 + r;
    float* ob = out + (size_t)(b * SQ_ + qrow) * D_ + h * DH_;
    #pragma unroll
    for (int nt = 0; nt < 4; ++nt)
      ob[nt * 16 + l16] = o_acc[nt][r] * inv;
  }
}

// ---------------------------------------------------------------------------
// Fallback path (workspace too small for bitmask): round-2 kernel, unchanged.
// ---------------------------------------------------------------------------
template<bool WS, bool MBYTE>
__device__ __forceinline__ void attn_body(
    const float* __restrict__ q, const float* __restrict__ k,
    const float* __restrict__ v, const void* __restrict__ mb,
    const float* __restrict__ msc, float* __restrict__ out,
    const _Float16* __restrict__ k16, const _Float16* __restrict__ vt16,
    _Float16 (&ps)[4][16][34]) {
  const int tid  = threadIdx.x;
  const int wave = tid >> 6;
  const int lane = tid & 63;
  const int l16  = lane & 15;
  const int g4   = lane >> 4;
  const int b  = blockIdx.z;
  const int h  = blockIdx.y;
  const int q0 = blockIdx.x * 64;
  const int bh = b * H_ + h;

  half8 aq[2];
  {
    const float* qp = q + ((size_t)(b * SQ_ + q0 + wave * 16 + l16)) * D_ + h * DH_;
    #pragma unroll
    for (int kk = 0; kk < 2; ++kk) {
      float4 f0 = *reinterpret_cast<const float4*>(qp + kk * 32 + g4 * 8);
      float4 f1 = *reinterpret_cast<const float4*>(qp + kk * 32 + g4 * 8 + 4);
      aq[kk] = cvt8(f0, f1);
    }
  }

  floatx4 o_acc[4];
  floatx4 l_acc;
  #pragma unroll
  for (int nt = 0; nt < 4; ++nt)
    #pragma unroll
    for (int r = 0; r < 4; ++r) o_acc[nt][r] = 0.0f;
  #pragma unroll
  for (int r = 0; r < 4; ++r) l_acc[r] = 0.0f;
  float m2[4] = {-1e30f, -1e30f, -1e30f, -1e30f};

  unsigned int rowoff[4];
  #pragma unroll
  for (int r = 0; r < 4; ++r) {
    int qrow = q0 + wave * 16 + g4 * 4 + r;
    rowoff[r] = (unsigned int)((b * H_ + h) * SQ_ + qrow) * SK_;
  }

  half8 ones_f;
  #pragma unroll
  for (int j = 0; j < 8; ++j) ones_f[j] = (_Float16)1.0f;
  const float c2 = 0.18033688011112042f;

  const unsigned char* mbb = (const unsigned char*)mb;
  const unsigned int*  mbd = (const unsigned int*)mb;

  auto load_masks = [&](int kt_, float (&m_)[2][4]) {
    #pragma unroll
    for (int ct = 0; ct < 2; ++ct)
      #pragma unroll
      for (int r = 0; r < 4; ++r) {
        int col = kt_ * 32 + ct * 16 + l16;
        int cc  = col < SK_ ? col : SK_ - 1;
        unsigned int idx = rowoff[r] + (unsigned int)cc;
        float sc = msc[idx];
        unsigned int mvv = MBYTE ? (unsigned int)mbb[idx] : mbd[idx];
        m_[ct][r] = (mvv != 0u && col < SK_) ? sc : 0.0f;
      }
  };

  float mC[2][4];
  load_masks(0, mC);

  const _Float16* kbase16 = k16 + (size_t)bh * SKP_ * DH_;
  const _Float16* vbase16 = vt16 + (size_t)bh * DH_ * SKP_;
  const float* kbase = k + (size_t)(b * SK_) * D_ + h * DH_;
  const float* vbase = v + (size_t)(b * SK_) * D_ + h * DH_;

  for (int kt = 0; kt < KT_; ++kt) {
    half8 kbf[2][2];
    if constexpr (WS) {
      const _Float16* kp = kbase16 + (size_t)(kt * 32) * DH_;
      #pragma unroll
      for (int ct = 0; ct < 2; ++ct)
        #pragma unroll
        for (int kk = 0; kk < 2; ++kk)
          kbf[ct][kk] = *reinterpret_cast<const half8*>(
              kp + (ct * 16 + l16) * DH_ + kk * 32 + g4 * 8);
    } else {
      #pragma unroll
      for (int ct = 0; ct < 2; ++ct) {
        int key = kt * 32 + ct * 16 + l16;
        int kc  = key < SK_ ? key : SK_ - 1;
        #pragma unroll
        for (int kk = 0; kk < 2; ++kk) {
          const float* kp = kbase + (size_t)kc * D_ + kk * 32 + g4 * 8;
          float4 f0 = *reinterpret_cast<const float4*>(kp);
          float4 f1 = *reinterpret_cast<const float4*>(kp + 4);
          kbf[ct][kk] = cvt8(f0, f1);
        }
      }
    }
    half8 vbf[4];
    if constexpr (WS) {
      const _Float16* vp = vbase16 + kt * 32 + g4 * 8;
      #pragma unroll
      for (int nt = 0; nt < 4; ++nt)
        vbf[nt] = *reinterpret_cast<const half8*>(vp + (size_t)(nt * 16 + l16) * SKP_);
    } else {
      #pragma unroll
      for (int nt = 0; nt < 4; ++nt) {
        int dim = nt * 16 + l16;
        #pragma unroll
        for (int j = 0; j < 8; ++j) {
          int key = kt * 32 + g4 * 8 + j;
          vbf[nt][j] = (key < SK_)
                         ? (_Float16)vbase[(size_t)key * D_ + dim]
                         : (_Float16)0.0f;
        }
      }
    }

    float mN[2][4];
    if (kt + 1 < KT_) load_masks(kt + 1, mN);

    floatx4 s[2];
    #pragma unroll
    for (int ct = 0; ct < 2; ++ct)
      #pragma unroll
      for (int r = 0; r < 4; ++r) s[ct][r] = 0.0f;
    #pragma unroll
    for (int ct = 0; ct < 2; ++ct)
      #pragma unroll
      for (int kk = 0; kk < 2; ++kk)
        s[ct] = __builtin_amdgcn_mfma_f32_16x16x32_f16(aq[kk], kbf[ct][kk], s[ct], 0, 0, 0);

    float pw[2][4];
    #pragma unroll
    for (int r = 0; r < 4; ++r) {
      float sc0 = mC[0][r], sc1 = mC[1][r];
      float s0 = (sc0 != 0.0f) ? s[0][r] * (c2 * sc0) : -1e30f;
      float s1 = (sc1 != 0.0f) ? s[1][r] * (c2 * sc1) : -1e30f;
      float mx = fmaxf(s0, s1);
      mx = fmaxf(mx, __shfl_xor(mx, 1));
      mx = fmaxf(mx, __shfl_xor(mx, 2));
      mx = fmaxf(mx, __shfl_xor(mx, 4));
      mx = fmaxf(mx, __shfl_xor(mx, 8));
      float mnew  = fmaxf(m2[r], mx);
      float alpha = exp2f(m2[r] - mnew);
      m2[r] = mnew;
      pw[0][r] = exp2f(s0 - mnew);
      pw[1][r] = exp2f(s1 - mnew);
      l_acc[r] *= alpha;
      #pragma unroll
      for (int nt = 0; nt < 4; ++nt) o_acc[nt][r] *= alpha;
    }

    #pragma unroll
    for (int ct = 0; ct < 2; ++ct)
      #pragma unroll
      for (int r = 0; r < 4; ++r)
        ps[wave][g4 * 4 + r][ct * 16 + l16] = (_Float16)pw[ct][r];
    asm volatile("s_waitcnt lgkmcnt(0)" ::: "memory");
    half8 pa;
    #pragma unroll
    for (int j = 0; j < 8; ++j) pa[j] = ps[wave][l16][g4 * 8 + j];

    #pragma unroll
    for (int nt = 0; nt < 4; ++nt)
      o_acc[nt] = __builtin_amdgcn_mfma_f32_16x16x32_f16(pa, vbf[nt], o_acc[nt], 0, 0, 0);
    l_acc = __builtin_amdgcn_mfma_f32_16x16x32_f16(pa, ones_f, l_acc, 0, 0, 0);

    if (kt + 1 < KT_) {
      #pragma unroll
      for (int ct = 0; ct < 2; ++ct)
        #pragma unroll
        for (int r = 0; r < 4; ++r) mC[ct][r] = mN[ct][r];
    }
  }

  #pragma unroll
  for (int r = 0; r < 4; ++r) {
    float inv = 1.0f / l_acc[r];
    int qrow = q0 + wave * 16 + g4 * 4 + r;
    float* ob = out + (size_t)(b * SQ_ + qrow) * D_ + h * DH_;
    #pragma unroll
    for (int nt = 0; nt < 4; ++nt)
      ob[nt * 16 + l16] = o_acc[nt][r] * inv;
  }
}

template<bool WS>
__global__ __launch_bounds__(256, 3)
void attn_fwd(const float* __restrict__ q, const float* __restrict__ k,
              const float* __restrict__ v, const void* __restrict__ mb,
              const float* __restrict__ msc, float* __restrict__ out,
              const _Float16* __restrict__ k16, const _Float16* __restrict__ vt16) {
  __shared__ __align__(16) _Float16 ps[4][16][34];
  if (g_mask_fmt == 1) attn_body<WS, true >(q, k, v, mb, msc, out, k16, vt16, ps);
  else                 attn_body<WS, false>(q, k, v, mb, msc, out, k16, vt16, ps);
}

extern "C" void kernel_launch(void* const* d_in, const int* in_sizes, int n_in,
                              void* d_out, int out_size, void* d_ws, size_t ws_size,
                              hipStream_t stream) {
  const float* q   = (const float*)d_in[0];
  const float* k   = (const float*)d_in[1];
  const float* v   = (const float*)d_in[2];
  const void*  mb  = d_in[3];
  const float* msc = (const float*)d_in[4];
  float* out = (float*)d_out;

  detect_mask_fmt<<<1, 256, 0, stream>>>((const unsigned int*)mb);

  _Float16* k16  = (_Float16*)d_ws;
  _Float16* vt16 = k16 + K16_ELEMS;
  unsigned int* mbits = (unsigned int*)(vt16 + K16_ELEMS);

  dim3 grid(SQ_ / 64, H_, B_);
  if (d_ws != nullptr && ws_size >= WS_FULL) {
    convert_kv<<<1200, 256, 0, stream>>>(k, v, k16, vt16);
    build_mbits<<<2560, 256, 0, stream>>>(mb, mbits);   // 10240 waves x 16 rows
    attn_fwd_full<<<grid, 256, 0, stream>>>(q, msc, out, k16, vt16, mbits);
  } else if (d_ws != nullptr && ws_size >= WS_KV) {
    convert_kv<<<1200, 256, 0, stream>>>(k, v, k16, vt16);
    attn_fwd<true><<<grid, 256, 0, stream>>>(q, k, v, mb, msc, out, k16, vt16);
  } else {
    attn_fwd<false><<<grid, 256, 0, stream>>>(q, k, v, mb, msc, out, k16, vt16);
  }
}

// Round 4
// 715.507 us; speedup vs baseline: 1.1649x; 1.1491x over previous
//
#include <hip/hip_runtime.h>

// Problem constants (fixed by the reference)
#define B_  4
#define SQ_ 4096
#define SK_ 462
#define H_  10
#define DH_ 64
#define D_  (H_ * DH_)   // 640
#define SKP_ 480         // keys padded to 15*32
#define KT_  15          // key chunks of 32

typedef _Float16 half8 __attribute__((ext_vector_type(8)));
typedef float floatx4 __attribute__((ext_vector_type(4)));
typedef float float2v __attribute__((ext_vector_type(2)));

// workspace layout: f16 K | f16 V^T
#define K16_ELEMS ((size_t)B_ * H_ * SKP_ * DH_)            // 1,228,800 halves
#define WS_KV     (2 * K16_ELEMS * sizeof(_Float16))        // 4.9 MB

// mask_bool storage format: 0 = int32, 1 = byte, 2 = float32 per element.
// (0 and 2 both decode as "dword != 0".)
__device__ int g_mask_fmt;

__global__ void detect_mask_fmt(const unsigned int* __restrict__ mb_dw) {
  __shared__ int s_float, s_byte;
  if (threadIdx.x == 0) { s_float = 0; s_byte = 0; }
  __syncthreads();
  int fl = 0, by = 0;
  for (int i = threadIdx.x; i < 1024; i += 256) {
    unsigned int x = mb_dw[i];
    if (x > 1u) {
      if (x == 0x3F800000u) fl = 1; else by = 1;
    }
  }
  if (fl) atomicOr(&s_float, 1);
  if (by) atomicOr(&s_byte, 1);
  __syncthreads();
  if (threadIdx.x == 0) g_mask_fmt = s_float ? 2 : (s_byte ? 1 : 0);
}

__device__ __forceinline__ half8 cvt8(float4 a, float4 b) {
  half8 o;
  o[0] = (_Float16)a.x; o[1] = (_Float16)a.y;
  o[2] = (_Float16)a.z; o[3] = (_Float16)a.w;
  o[4] = (_Float16)b.x; o[5] = (_Float16)b.y;
  o[6] = (_Float16)b.z; o[7] = (_Float16)b.w;
  return o;
}

// ---------------------------------------------------------------------------
// One-time K/V conversion:
//   k16 [b][h][key(480)][d(64)]  f16 -> QK^T B-fragments = dwordx4
//   vt16[b][h][d(64)][key(480)]  f16 -> PV   B-fragments = dwordx4
// Padding keys 462..479 are zero (V MUST be zero so P=0 rows stay finite).
// ---------------------------------------------------------------------------
__global__ void convert_kv(const float* __restrict__ k, const float* __restrict__ v,
                           _Float16* __restrict__ k16, _Float16* __restrict__ vt16) {
  int t = blockIdx.x * 256 + threadIdx.x;
  const int NK = B_ * H_ * SKP_ * (DH_ / 8);
  const int NV = B_ * H_ * DH_ * (SKP_ / 8);
  if (t < NK) {
    int d8  = t & 7;
    int key = (t >> 3) % SKP_;
    int bh  = t / (8 * SKP_);
    int b = bh / H_, h = bh % H_;
    half8 o;
    if (key < SK_) {
      const float* src = k + ((size_t)(b * SK_ + key)) * D_ + h * DH_ + d8 * 8;
      float4 f0 = *reinterpret_cast<const float4*>(src);
      float4 f1 = *reinterpret_cast<const float4*>(src + 4);
      o = cvt8(f0, f1);
    } else {
      #pragma unroll
      for (int j = 0; j < 8; ++j) o[j] = (_Float16)0.0f;
    }
    *reinterpret_cast<half8*>(k16 + ((size_t)bh * SKP_ + key) * DH_ + d8 * 8) = o;
  } else if (t < NK + NV) {
    int u  = t - NK;
    int k8 = u % (SKP_ / 8);
    int d  = (u / (SKP_ / 8)) % DH_;
    int bh = u / ((SKP_ / 8) * DH_);
    int b = bh / H_, h = bh % H_;
    half8 o;
    #pragma unroll
    for (int j = 0; j < 8; ++j) {
      int key = k8 * 8 + j;
      o[j] = (key < SK_)
               ? (_Float16)v[((size_t)(b * SK_ + key)) * D_ + h * DH_ + d]
               : (_Float16)0.0f;
    }
    *reinterpret_cast<half8*>(vt16 + ((size_t)bh * DH_ + d) * SKP_ + k8 * 8) = o;
  }
}

// ---------------------------------------------------------------------------
// Pipelined flash attention, barrier-free. grid=(SQ/64,H,B), block=256 (4
// independent waves, 16 q-rows each). Per iteration, the HBM stream
// (mask_scale float2 + mask pair) for iteration kt+2 is issued mid-body into
// the register buffer freed one iteration ago; nothing in iteration kt waits
// on loads issued in iteration kt. Issue order pinned with sched_barrier(0):
//   [K,V frag loads (L2)] < [msc+mask issue] < [MFMA/softmax/PV] < [fold+write]
// The ms tile uses an XOR column-pair swizzle (cp ^ (row&3)<<2) to spread
// ds_write_b64 banks. mfma_f32_16x16x32_f16 layouts:
//   A[m=lane&15][k=(lane>>4)*8+j], B[k][n=lane&15], C/D col=lane&15,
//   row=(lane>>4)*4+reg.
// ---------------------------------------------------------------------------
template<bool MBYTE>
__device__ __forceinline__ void attn_full_body(
    const float* __restrict__ q, const void* __restrict__ mb,
    const float* __restrict__ msc, float* __restrict__ out,
    const _Float16* __restrict__ k16, const _Float16* __restrict__ vt16,
    _Float16 (&ps)[4][16][34], float (&ms)[4][16][34]) {
  const int tid  = threadIdx.x;
  const int wave = tid >> 6;
  const int lane = tid & 63;
  const int l16  = lane & 15;
  const int g4   = lane >> 4;

  const int b  = blockIdx.z;
  const int h  = blockIdx.y;
  const int q0 = blockIdx.x * 64;
  const int bh = b * H_ + h;

  // ---- Q A-fragments straight from global (one-time, 16B-aligned) ----
  half8 aq[2];
  {
    const float* qp = q + ((size_t)(b * SQ_ + q0 + wave * 16 + l16)) * D_ + h * DH_;
    #pragma unroll
    for (int kk = 0; kk < 2; ++kk) {
      float4 f0 = *reinterpret_cast<const float4*>(qp + kk * 32 + g4 * 8);
      float4 f1 = *reinterpret_cast<const float4*>(qp + kk * 32 + g4 * 8 + 4);
      aq[kk] = cvt8(f0, f1);
    }
  }

  floatx4 o_acc[4];
  floatx4 l_acc;
  #pragma unroll
  for (int nt = 0; nt < 4; ++nt)
    #pragma unroll
    for (int r = 0; r < 4; ++r) o_acc[nt][r] = 0.0f;
  #pragma unroll
  for (int r = 0; r < 4; ++r) l_acc[r] = 0.0f;
  float m2[4] = {-1e30f, -1e30f, -1e30f, -1e30f};   // running max, base-2 domain

  half8 ones_f;
  #pragma unroll
  for (int j = 0; j < 8; ++j) ones_f[j] = (_Float16)1.0f;

  const float c2 = 0.18033688011112042f;  // (1/sqrt(64)) * log2(e)

  const unsigned char* mbb = (const unsigned char*)mb;
  const unsigned int*  mbd = (const unsigned int*)mb;

  // loader row for this lane: row i = lane>>2 of the wave's 16 q-rows
  const size_t mrow = ((size_t)bh * SQ_ + (q0 + wave * 16 + (lane >> 2))) * SK_;

  struct Buf {
    float2v      sc[4];   // msc pairs
    uint2        mk2[4];  // mask pairs (dword formats)
    unsigned int mk1[4];  // mask pairs (byte format, 2 bytes in low 16)
  };
  Buf bufA, bufB;

  // issue msc+mask loads for chunk kt_ (cols kt_*32 + cp*2, cp=(lane&3)+4p)
  auto ISSUE = [&](int kt_, Buf& bf) {
    #pragma unroll
    for (int p = 0; p < 4; ++p) {
      int cp = (lane & 3) + p * 4;
      int c  = kt_ * 32 + cp * 2;
      int cc = (c <= SK_ - 2) ? c : (SK_ - 2);   // even clamp: 8B align kept
      bf.sc[p] = *reinterpret_cast<const float2v*>(msc + mrow + cc);
      if constexpr (MBYTE)
        bf.mk1[p] = *reinterpret_cast<const unsigned short*>(mbb + mrow + cc);
      else
        bf.mk2[p] = *reinterpret_cast<const uint2*>(mbd + mrow + cc);
    }
  };

  // fold mask into scale (0 <=> masked; msc >= 1) and write swizzled tile
  auto FOLD_WRITE = [&](int kt_, Buf& bf) {
    int i = lane >> 2;
    #pragma unroll
    for (int p = 0; p < 4; ++p) {
      int cp = (lane & 3) + p * 4;
      int c  = kt_ * 32 + cp * 2;
      float v0 = bf.sc[p][0], v1 = bf.sc[p][1];
      unsigned int b0, b1;
      if constexpr (MBYTE) { b0 = bf.mk1[p] & 0xFFu; b1 = bf.mk1[p] >> 8; }
      else                 { b0 = bf.mk2[p].x;       b1 = bf.mk2[p].y;    }
      v0 = (b0 != 0u && c     < SK_) ? v0 : 0.0f;
      v1 = (b1 != 0u && c + 1 < SK_) ? v1 : 0.0f;
      int cps = cp ^ ((i & 3) << 2);
      float2v t; t[0] = v0; t[1] = v1;
      *reinterpret_cast<float2v*>(&ms[wave][i][cps * 2]) = t;
    }
  };

  const _Float16* kbase16 = k16 + (size_t)bh * SKP_ * DH_;
  const _Float16* vbase16 = vt16 + (size_t)bh * DH_ * SKP_;

  // ---- prologue: msc(0)->bufB, msc(1)->bufA, tile <- msc(0) ----
  ISSUE(0, bufB);
  ISSUE(1, bufA);
  FOLD_WRITE(0, bufB);

  auto ITER = [&](int kt, Buf& rCur, Buf& rNxt) {
    // ---- 1) K/V fragments from workspace f16 (L2-resident) ----
    half8 kbf[2][2];
    {
      const _Float16* kp = kbase16 + (size_t)(kt * 32) * DH_;
      #pragma unroll
      for (int ct = 0; ct < 2; ++ct)
        #pragma unroll
        for (int kk = 0; kk < 2; ++kk)
          kbf[ct][kk] = *reinterpret_cast<const half8*>(
              kp + (ct * 16 + l16) * DH_ + kk * 32 + g4 * 8);
    }
    half8 vbf[4];
    {
      const _Float16* vp = vbase16 + kt * 32 + g4 * 8;
      #pragma unroll
      for (int nt = 0; nt < 4; ++nt)
        vbf[nt] = *reinterpret_cast<const half8*>(vp + (size_t)(nt * 16 + l16) * SKP_);
    }
    __builtin_amdgcn_sched_barrier(0);   // K/V issued BEFORE msc (vmcnt order)

    // ---- 2) issue msc+mask for kt+2 into the freed buffer ----
    if (kt + 2 < KT_) ISSUE(kt + 2, rNxt);
    __builtin_amdgcn_sched_barrier(0);   // keep issue here; don't sink below

    // ---- 3) S = Q K^T ----
    floatx4 s[2];
    #pragma unroll
    for (int ct = 0; ct < 2; ++ct)
      #pragma unroll
      for (int r = 0; r < 4; ++r) s[ct][r] = 0.0f;
    #pragma unroll
    for (int ct = 0; ct < 2; ++ct)
      #pragma unroll
      for (int kk = 0; kk < 2; ++kk)
        s[ct] = __builtin_amdgcn_mfma_f32_16x16x32_f16(aq[kk], kbf[ct][kk], s[ct], 0, 0, 0);

    // ---- 4) read folded scales from swizzled tile (0 <=> masked) ----
    float mC[2][4];
    #pragma unroll
    for (int r = 0; r < 4; ++r) {
      int row = g4 * 4 + r;
      int cps0 = (l16 >> 1) ^ (r << 2);
      int cps1 = (8 + (l16 >> 1)) ^ (r << 2);
      mC[0][r] = ms[wave][row][cps0 * 2 + (l16 & 1)];
      mC[1][r] = ms[wave][row][cps1 * 2 + (l16 & 1)];
    }

    // ---- 5) online softmax (base-2) ----
    float pw[2][4];
    #pragma unroll
    for (int r = 0; r < 4; ++r) {
      float sc0 = mC[0][r], sc1 = mC[1][r];
      float s0 = (sc0 != 0.0f) ? s[0][r] * (c2 * sc0) : -1e30f;
      float s1 = (sc1 != 0.0f) ? s[1][r] * (c2 * sc1) : -1e30f;
      float mx = fmaxf(s0, s1);
      mx = fmaxf(mx, __shfl_xor(mx, 1));
      mx = fmaxf(mx, __shfl_xor(mx, 2));
      mx = fmaxf(mx, __shfl_xor(mx, 4));
      mx = fmaxf(mx, __shfl_xor(mx, 8));
      float mnew  = fmaxf(m2[r], mx);
      float alpha = exp2f(m2[r] - mnew);
      m2[r] = mnew;
      pw[0][r] = exp2f(s0 - mnew);   // masked: exp2(-1e30 - finite) == +0
      pw[1][r] = exp2f(s1 - mnew);
      l_acc[r] *= alpha;
      #pragma unroll
      for (int nt = 0; nt < 4; ++nt) o_acc[nt][r] *= alpha;
    }

    // ---- 6) P: C-layout -> A-layout via per-wave LDS (no barrier) ----
    #pragma unroll
    for (int ct = 0; ct < 2; ++ct)
      #pragma unroll
      for (int r = 0; r < 4; ++r)
        ps[wave][g4 * 4 + r][ct * 16 + l16] = (_Float16)pw[ct][r];
    asm volatile("s_waitcnt lgkmcnt(0)" ::: "memory");  // wave-local write->read
    half8 pa;
    #pragma unroll
    for (int j = 0; j < 8; ++j) pa[j] = ps[wave][l16][g4 * 8 + j];

    // ---- 7) O += P V ; l += rowsum(P) ----
    #pragma unroll
    for (int nt = 0; nt < 4; ++nt)
      o_acc[nt] = __builtin_amdgcn_mfma_f32_16x16x32_f16(pa, vbf[nt], o_acc[nt], 0, 0, 0);
    l_acc = __builtin_amdgcn_mfma_f32_16x16x32_f16(pa, ones_f, l_acc, 0, 0, 0);

    // ---- 8) fold+stage next tile (loads issued >= 1 iteration ago) ----
    if (kt + 1 < KT_) FOLD_WRITE(kt + 1, rCur);
  };

  #pragma unroll
  for (int kt = 0; kt < KT_; kt += 2) {
    ITER(kt, bufA, bufB);
    if (kt + 1 < KT_) ITER(kt + 1, bufB, bufA);
  }

  // ---- epilogue: normalize and store (16-lane, 64B coalesced segments) ----
  #pragma unroll
  for (int r = 0; r < 4; ++r) {
    float inv = 1.0f / l_acc[r];
    int qrow = q0 + wave * 16 + g4 * 4 + r;
    float* ob = out + (size_t)(b * SQ_ + qrow) * D_ + h * DH_;
    #pragma unroll
    for (int nt = 0; nt < 4; ++nt)
      ob[nt * 16 + l16] = o_acc[nt][r] * inv;
  }
}

__global__ __launch_bounds__(256, 3)
void attn_fwd_full(const float* __restrict__ q, const void* __restrict__ mb,
                   const float* __restrict__ msc, float* __restrict__ out,
                   const _Float16* __restrict__ k16, const _Float16* __restrict__ vt16) {
  __shared__ __align__(16) _Float16 ps[4][16][34];   // 4.25 KB
  __shared__ __align__(16) float    ms[4][16][34];   // 8.7 KB (swizzled tile)
  if (g_mask_fmt == 1) attn_full_body<true >(q, mb, msc, out, k16, vt16, ps, ms);
  else                 attn_full_body<false>(q, mb, msc, out, k16, vt16, ps, ms);
}

// ---------------------------------------------------------------------------
// Fallback (workspace too small for f16 K/V): reads f32 K/V directly, scalar
// mask loads. Known-correct from Round 2.
// ---------------------------------------------------------------------------
template<bool MBYTE>
__device__ __forceinline__ void attn_body_fb(
    const float* __restrict__ q, const float* __restrict__ k,
    const float* __restrict__ v, const void* __restrict__ mb,
    const float* __restrict__ msc, float* __restrict__ out,
    _Float16 (&ps)[4][16][34]) {
  const int tid  = threadIdx.x;
  const int wave = tid >> 6;
  const int lane = tid & 63;
  const int l16  = lane & 15;
  const int g4   = lane >> 4;
  const int b  = blockIdx.z;
  const int h  = blockIdx.y;
  const int q0 = blockIdx.x * 64;

  half8 aq[2];
  {
    const float* qp = q + ((size_t)(b * SQ_ + q0 + wave * 16 + l16)) * D_ + h * DH_;
    #pragma unroll
    for (int kk = 0; kk < 2; ++kk) {
      float4 f0 = *reinterpret_cast<const float4*>(qp + kk * 32 + g4 * 8);
      float4 f1 = *reinterpret_cast<const float4*>(qp + kk * 32 + g4 * 8 + 4);
      aq[kk] = cvt8(f0, f1);
    }
  }

  floatx4 o_acc[4];
  floatx4 l_acc;
  #pragma unroll
  for (int nt = 0; nt < 4; ++nt)
    #pragma unroll
    for (int r = 0; r < 4; ++r) o_acc[nt][r] = 0.0f;
  #pragma unroll
  for (int r = 0; r < 4; ++r) l_acc[r] = 0.0f;
  float m2[4] = {-1e30f, -1e30f, -1e30f, -1e30f};

  unsigned int rowoff[4];
  #pragma unroll
  for (int r = 0; r < 4; ++r) {
    int qrow = q0 + wave * 16 + g4 * 4 + r;
    rowoff[r] = (unsigned int)((b * H_ + h) * SQ_ + qrow) * SK_;
  }

  half8 ones_f;
  #pragma unroll
  for (int j = 0; j < 8; ++j) ones_f[j] = (_Float16)1.0f;
  const float c2 = 0.18033688011112042f;

  const unsigned char* mbb = (const unsigned char*)mb;
  const unsigned int*  mbd = (const unsigned int*)mb;

  auto load_masks = [&](int kt_, float (&m_)[2][4]) {
    #pragma unroll
    for (int ct = 0; ct < 2; ++ct)
      #pragma unroll
      for (int r = 0; r < 4; ++r) {
        int col = kt_ * 32 + ct * 16 + l16;
        int cc  = col < SK_ ? col : SK_ - 1;
        unsigned int idx = rowoff[r] + (unsigned int)cc;
        float sc = msc[idx];
        unsigned int mvv = MBYTE ? (unsigned int)mbb[idx] : mbd[idx];
        m_[ct][r] = (mvv != 0u && col < SK_) ? sc : 0.0f;
      }
  };

  float mC[2][4];
  load_masks(0, mC);

  const float* kbase = k + (size_t)(b * SK_) * D_ + h * DH_;
  const float* vbase = v + (size_t)(b * SK_) * D_ + h * DH_;

  for (int kt = 0; kt < KT_; ++kt) {
    half8 kbf[2][2];
    #pragma unroll
    for (int ct = 0; ct < 2; ++ct) {
      int key = kt * 32 + ct * 16 + l16;
      int kc  = key < SK_ ? key : SK_ - 1;
      #pragma unroll
      for (int kk = 0; kk < 2; ++kk) {
        const float* kp = kbase + (size_t)kc * D_ + kk * 32 + g4 * 8;
        float4 f0 = *reinterpret_cast<const float4*>(kp);
        float4 f1 = *reinterpret_cast<const float4*>(kp + 4);
        kbf[ct][kk] = cvt8(f0, f1);
      }
    }
    half8 vbf[4];
    #pragma unroll
    for (int nt = 0; nt < 4; ++nt) {
      int dim = nt * 16 + l16;
      #pragma unroll
      for (int j = 0; j < 8; ++j) {
        int key = kt * 32 + g4 * 8 + j;
        vbf[nt][j] = (key < SK_) ? (_Float16)vbase[(size_t)key * D_ + dim]
                                 : (_Float16)0.0f;
      }
    }

    float mN[2][4];
    if (kt + 1 < KT_) load_masks(kt + 1, mN);

    floatx4 s[2];
    #pragma unroll
    for (int ct = 0; ct < 2; ++ct)
      #pragma unroll
      for (int r = 0; r < 4; ++r) s[ct][r] = 0.0f;
    #pragma unroll
    for (int ct = 0; ct < 2; ++ct)
      #pragma unroll
      for (int kk = 0; kk < 2; ++kk)
        s[ct] = __builtin_amdgcn_mfma_f32_16x16x32_f16(aq[kk], kbf[ct][kk], s[ct], 0, 0, 0);

    float pw[2][4];
    #pragma unroll
    for (int r = 0; r < 4; ++r) {
      float sc0 = mC[0][r], sc1 = mC[1][r];
      float s0 = (sc0 != 0.0f) ? s[0][r] * (c2 * sc0) : -1e30f;
      float s1 = (sc1 != 0.0f) ? s[1][r] * (c2 * sc1) : -1e30f;
      float mx = fmaxf(s0, s1);
      mx = fmaxf(mx, __shfl_xor(mx, 1));
      mx = fmaxf(mx, __shfl_xor(mx, 2));
      mx = fmaxf(mx, __shfl_xor(mx, 4));
      mx = fmaxf(mx, __shfl_xor(mx, 8));
      float mnew  = fmaxf(m2[r], mx);
      float alpha = exp2f(m2[r] - mnew);
      m2[r] = mnew;
      pw[0][r] = exp2f(s0 - mnew);
      pw[1][r] = exp2f(s1 - mnew);
      l_acc[r] *= alpha;
      #pragma unroll
      for (int nt = 0; nt < 4; ++nt) o_acc[nt][r] *= alpha;
    }

    #pragma unroll
    for (int ct = 0; ct < 2; ++ct)
      #pragma unroll
      for (int r = 0; r < 4; ++r)
        ps[wave][g4 * 4 + r][ct * 16 + l16] = (_Float16)pw[ct][r];
    asm volatile("s_waitcnt lgkmcnt(0)" ::: "memory");
    half8 pa;
    #pragma unroll
    for (int j = 0; j < 8; ++j) pa[j] = ps[wave][l16][g4 * 8 + j];

    #pragma unroll
    for (int nt = 0; nt < 4; ++nt)
      o_acc[nt] = __builtin_amdgcn_mfma_f32_16x16x32_f16(pa, vbf[nt], o_acc[nt], 0, 0, 0);
    l_acc = __builtin_amdgcn_mfma_f32_16x16x32_f16(pa, ones_f, l_acc, 0, 0, 0);

    if (kt + 1 < KT_) {
      #pragma unroll
      for (int ct = 0; ct < 2; ++ct)
        #pragma unroll
        for (int r = 0; r < 4; ++r) mC[ct][r] = mN[ct][r];
    }
  }

  #pragma unroll
  for (int r = 0; r < 4; ++r) {
    float inv = 1.0f / l_acc[r];
    int qrow = q0 + wave * 16 + g4 * 4 + r;
    float* ob = out + (size_t)(b * SQ_ + qrow) * D_ + h * DH_;
    #pragma unroll
    for (int nt = 0; nt < 4; ++nt)
      ob[nt * 16 + l16] = o_acc[nt][r] * inv;
  }
}

__global__ __launch_bounds__(256, 3)
void attn_fwd_fb(const float* __restrict__ q, const float* __restrict__ k,
                 const float* __restrict__ v, const void* __restrict__ mb,
                 const float* __restrict__ msc, float* __restrict__ out) {
  __shared__ __align__(16) _Float16 ps[4][16][34];
  if (g_mask_fmt == 1) attn_body_fb<true >(q, k, v, mb, msc, out, ps);
  else                 attn_body_fb<false>(q, k, v, mb, msc, out, ps);
}

extern "C" void kernel_launch(void* const* d_in, const int* in_sizes, int n_in,
                              void* d_out, int out_size, void* d_ws, size_t ws_size,
                              hipStream_t stream) {
  const float* q   = (const float*)d_in[0];
  const float* k   = (const float*)d_in[1];
  const float* v   = (const float*)d_in[2];
  const void*  mb  = d_in[3];          // mask_bool: storage format auto-detected
  const float* msc = (const float*)d_in[4];
  // d_in[5] = heads (==10), constant for this problem
  float* out = (float*)d_out;

  detect_mask_fmt<<<1, 256, 0, stream>>>((const unsigned int*)mb);

  _Float16* k16  = (_Float16*)d_ws;
  _Float16* vt16 = k16 + K16_ELEMS;

  dim3 grid(SQ_ / 64, H_, B_);
  if (d_ws != nullptr && ws_size >= WS_KV) {
    convert_kv<<<1200, 256, 0, stream>>>(k, v, k16, vt16);
    attn_fwd_full<<<grid, 256, 0, stream>>>(q, mb, msc, out, k16, vt16);
  } else {
    attn_fwd_fb<<<grid, 256, 0, stream>>>(q, k, v, mb, msc, out);
  }
}